// Round 4
// baseline (306.370 us; speedup 1.0000x reference)
//
#include <hip/hip_runtime.h>

#define NC 6
#define NIC 3
#define EPS 1e-5f
// H*W = 512*512 = 2^18 pixels = 2^16 float4 chunks per plane
#define HW4_SHIFT 16
#define HW4 (1 << HW4_SHIFT)

typedef float vfloat4 __attribute__((ext_vector_type(4)));  // native vector for builtins

__global__ __launch_bounds__(256) void aff_softmax_kernel(
    const float4* __restrict__ x4,
    const float* __restrict__ w1, const float* __restrict__ b1,
    const float* __restrict__ g1, const float* __restrict__ be1,
    const float* __restrict__ m1, const float* __restrict__ v1,
    const float* __restrict__ w2, const float* __restrict__ b2,
    const float* __restrict__ g2, const float* __restrict__ be2,
    const float* __restrict__ m2, const float* __restrict__ v2,
    vfloat4* __restrict__ out4)
{
    // Each block covers 512 consecutive float4 chunks of the output plane
    // (2 per thread, +256 apart so each load instruction is wave-contiguous).
    // 65536 % 512 == 0 -> a block never crosses a batch boundary.
    const unsigned t  = threadIdx.x;
    const unsigned c0 = blockIdx.x * 512u + t;   // chunk A
    const unsigned c1 = c0 + 256u;               // chunk B
    const unsigned b  = c0 >> HW4_SHIFT;         // batch
    const unsigned hw = c0 & (HW4 - 1u);         // float4 offset within plane

    const float4* xb = x4 + (b * (NC << HW4_SHIFT) + hw);

    // ---- Issue all 12 plane loads first: 12 KB in flight per wave ----
    float4 va[NC], vb[NC];
#pragma unroll
    for (int c = 0; c < NC; ++c) {
        va[c] = xb[(unsigned)(c << HW4_SHIFT)];
        vb[c] = xb[(unsigned)(c << HW4_SHIFT) + 256u];
    }

    // ---- Fold BN1 into conv1, BN2 into conv2 (uniform scalars; overlaps
    //      the global-load latency) ----
    float W1f[NIC][NC], B1f[NIC];
#pragma unroll
    for (int o = 0; o < NIC; ++o) {
        const float inv = g1[o] * rsqrtf(v1[o] + EPS);
        B1f[o] = b1[o] * inv + (be1[o] - m1[o] * inv);
#pragma unroll
        for (int c = 0; c < NC; ++c) W1f[o][c] = w1[o * NC + c] * inv;
    }
    float W2f[NC][NIC], B2f[NC];
#pragma unroll
    for (int o = 0; o < NC; ++o) {
        const float inv = g2[o] * rsqrtf(v2[o] + EPS);
        B2f[o] = b2[o] * inv + (be2[o] - m2[o] * inv);
#pragma unroll
        for (int c = 0; c < NIC; ++c) W2f[o][c] = w2[o * NIC + c] * inv;
    }

    // ---- Transpose chunks into per-pixel channel vectors (registers only) ----
    float xp[8][NC];
#pragma unroll
    for (int c = 0; c < NC; ++c) {
        xp[0][c] = va[c].x; xp[1][c] = va[c].y;
        xp[2][c] = va[c].z; xp[3][c] = va[c].w;
        xp[4][c] = vb[c].x; xp[5][c] = vb[c].y;
        xp[6][c] = vb[c].z; xp[7][c] = vb[c].w;
    }

    float r[8];
#pragma unroll
    for (int i = 0; i < 8; ++i) {
        // conv1 + BN1 + ReLU
        float h1[NIC];
#pragma unroll
        for (int o = 0; o < NIC; ++o) {
            float a = B1f[o];
#pragma unroll
            for (int c = 0; c < NC; ++c) a = fmaf(W1f[o][c], xp[i][c], a);
            h1[o] = fmaxf(a, 0.0f);
        }
        // conv2 + BN2, track max for stable softmax
        float h2[NC];
        float mx = -3.4e38f;
#pragma unroll
        for (int o = 0; o < NC; ++o) {
            float a = B2f[o];
#pragma unroll
            for (int c = 0; c < NIC; ++c) a = fmaf(W2f[o][c], h1[c], a);
            h2[o] = a;
            mx = fmaxf(mx, a);
        }
        // softmax fused with weighted channel-sum
        float sum = 0.0f, acc = 0.0f;
#pragma unroll
        for (int o = 0; o < NC; ++o) {
            const float e = __expf(h2[o] - mx);
            sum += e;
            acc = fmaf(e, xp[i][o], acc);
        }
        r[i] = acc * __builtin_amdgcn_rcpf(sum);  // sum in [1,6]; approx rcp ok
    }

    // ---- Nontemporal stores: output is never re-read by this kernel ----
    vfloat4 ra, rb;
    ra.x = r[0]; ra.y = r[1]; ra.z = r[2]; ra.w = r[3];
    rb.x = r[4]; rb.y = r[5]; rb.z = r[6]; rb.w = r[7];
    __builtin_nontemporal_store(ra, &out4[c0]);
    __builtin_nontemporal_store(rb, &out4[c1]);
}

extern "C" void kernel_launch(void* const* d_in, const int* in_sizes, int n_in,
                              void* d_out, int out_size, void* d_ws, size_t ws_size,
                              hipStream_t stream) {
    const float4* x4  = (const float4*)d_in[0];
    const float* w1  = (const float*)d_in[1];
    const float* b1  = (const float*)d_in[2];
    const float* g1  = (const float*)d_in[3];
    const float* be1 = (const float*)d_in[4];
    const float* m1  = (const float*)d_in[5];
    const float* v1  = (const float*)d_in[6];
    const float* w2  = (const float*)d_in[7];
    const float* b2  = (const float*)d_in[8];
    const float* g2  = (const float*)d_in[9];
    const float* be2 = (const float*)d_in[10];
    const float* m2  = (const float*)d_in[11];
    const float* v2  = (const float*)d_in[12];
    vfloat4* out4 = (vfloat4*)d_out;

    // out_size = 32*512*512 px = 2,097,152 float4 chunks; 512 chunks/block
    const int threads = 256;
    const int blocks  = (out_size / 4) / 512;   // 4096

    aff_softmax_kernel<<<blocks, threads, 0, stream>>>(
        x4, w1, b1, g1, be1, m1, v1, w2, b2, g2, be2, m2, v2, out4);
}